// Round 3
// baseline (105.069 us; speedup 1.0000x reference)
//
#include <hip/hip_runtime.h>

#define C_DIM 512
#define HID   256
#define B_DIM 8
#define L_DIM 196
#define LT    14              // l-tile per block (196 = 14*14)
#define NCH   4               // c-split chunks per block (phase 1)
#define CCH   (C_DIM/NCH)     // 128 c per chunk
#define HHALF 128             // h-half per block (phase 1)
#define NJC   7               // j-chunks (phase 2)
#define JCL   (L_DIM/NJC)     // 28 j per chunk
#define NIW   49              // i-groups of 4 rows (phase 2)
#define PAIR_BLOCKS ((B_DIM*NJC*NIW)/4)   // 686

#define P_ELEMS        (B_DIM*L_DIM*HID)  // 401408
#define PARTIAL_ELEMS  (B_DIM*NJC*L_DIM)  // 10976

// Phase 1: p1[b,l,h] = sum_c f1[b,c,l]*W1[c,h] + b1[h]
//          p2[b,l,h] = sum_c f2[b,c,l]*W1[C+c,h]
// grid = (112*2, 2) blocks of 512: tid = (chunk:2 | h_local:7).
// Each block: one (b, l-tile, h-half, which); 4-way c-split, LDS tree-combine.
__global__ __launch_bounds__(512) void compute_p_kernel(
    const float* __restrict__ f1, const float* __restrict__ f2,
    const float* __restrict__ W1, const float* __restrict__ b1,
    float* __restrict__ p1, float* __restrict__ p2,
    int* __restrict__ counter) {
  if (blockIdx.x == 0 && blockIdx.y == 0 && threadIdx.x == 0) *counter = 0;

  const int which = blockIdx.y;
  const int hh = blockIdx.x & 1;
  const int bt = blockIdx.x >> 1;               // 0..111
  const int b  = bt / 14;
  const int l0 = (bt % 14) * LT;
  const int h_local = threadIdx.x & (HHALF - 1);
  const int chunk   = threadIdx.x >> 7;         // 0..3
  const int h = hh * HHALF + h_local;

  const float* __restrict__ f = which ? f2 : f1;
  const float* __restrict__ W = W1 + which * C_DIM * HID;
  float* __restrict__ p = which ? p2 : p1;

  __shared__ float fv[C_DIM][16];               // 32 KB; lt padded 14->16
  float (*comb)[HHALF][LT + 1] = (float (*)[HHALF][LT + 1])fv;  // aliased after c-loop

  for (int idx = threadIdx.x; idx < C_DIM * LT; idx += 512) {
    const int c  = idx / LT;
    const int lt = idx - c * LT;
    fv[c][lt] = f[(b * C_DIM + c) * L_DIM + l0 + lt];
  }

  float acc[LT];
  #pragma unroll
  for (int lt = 0; lt < LT; ++lt) acc[lt] = 0.0f;
  __syncthreads();

  const float* __restrict__ Wc = W + (chunk * CCH) * HID + h;
  const float4* __restrict__ fr = (const float4*)fv[chunk * CCH];
  #pragma unroll 4
  for (int c = 0; c < CCH; ++c) {
    const float w = Wc[c * HID];                // coalesced over h
    const float4 v0 = fr[c * 4 + 0];            // LDS broadcast b128 reads
    const float4 v1 = fr[c * 4 + 1];
    const float4 v2 = fr[c * 4 + 2];
    const float4 v3 = fr[c * 4 + 3];
    acc[ 0] = fmaf(v0.x, w, acc[ 0]);
    acc[ 1] = fmaf(v0.y, w, acc[ 1]);
    acc[ 2] = fmaf(v0.z, w, acc[ 2]);
    acc[ 3] = fmaf(v0.w, w, acc[ 3]);
    acc[ 4] = fmaf(v1.x, w, acc[ 4]);
    acc[ 5] = fmaf(v1.y, w, acc[ 5]);
    acc[ 6] = fmaf(v1.z, w, acc[ 6]);
    acc[ 7] = fmaf(v1.w, w, acc[ 7]);
    acc[ 8] = fmaf(v2.x, w, acc[ 8]);
    acc[ 9] = fmaf(v2.y, w, acc[ 9]);
    acc[10] = fmaf(v2.z, w, acc[10]);
    acc[11] = fmaf(v2.w, w, acc[11]);
    acc[12] = fmaf(v3.x, w, acc[12]);
    acc[13] = fmaf(v3.y, w, acc[13]);
  }

  __syncthreads();                              // fv dead; reuse as comb
  if (chunk >= 2) {
    #pragma unroll
    for (int lt = 0; lt < LT; ++lt) comb[chunk - 2][h_local][lt] = acc[lt];
  }
  __syncthreads();
  if (chunk < 2) {
    #pragma unroll
    for (int lt = 0; lt < LT; ++lt) acc[lt] += comb[chunk][h_local][lt];
  }
  __syncthreads();
  if (chunk == 1) {
    #pragma unroll
    for (int lt = 0; lt < LT; ++lt) comb[0][h_local][lt] = acc[lt];
  }
  __syncthreads();
  if (chunk == 0) {
    const float bias = which ? 0.0f : b1[h];    // fold b1 into p1 only
    #pragma unroll
    for (int lt = 0; lt < LT; ++lt)
      p[(b * L_DIM + l0 + lt) * HID + h] = acc[lt] + comb[0][h_local][lt] + bias;
  }
}

// Phase 2 (+fused final reduce): wave = 4 i-rows x one 28-j chunk.
// partial[b,jc,i] = sum_{j in chunk} relu(p1[b,i,:]+p2[b,j,:]).W2
// Last-finishing block (ticket) reduces all partials in fixed order -> out.
__global__ __launch_bounds__(256) void pair_kernel(
    const float* __restrict__ p1, const float* __restrict__ p2,
    const float* __restrict__ W2, const float* __restrict__ b2,
    float* __restrict__ partial, int* __restrict__ counter,
    float* __restrict__ out) {
  const int lane = threadIdx.x & 63;
  const int wid  = blockIdx.x * 4 + (threadIdx.x >> 6);
  const int b  = wid / (NJC * NIW);
  const int r  = wid % (NJC * NIW);
  const int jc = r / NIW;                       // same for all 4 waves of a block
  const int wi = r % NIW;

  const float4 w = *(const float4*)(W2 + lane * 4);
  const float* __restrict__ p1b = p1 + (b * L_DIM) * HID + lane * 4;
  const float4 a0 = *(const float4*)(p1b + (wi          ) * HID);
  const float4 a1 = *(const float4*)(p1b + (wi + 1 * NIW) * HID);
  const float4 a2 = *(const float4*)(p1b + (wi + 2 * NIW) * HID);
  const float4 a3 = *(const float4*)(p1b + (wi + 3 * NIW) * HID);

  const float4* __restrict__ vp =
      (const float4*)(p2 + (b * L_DIM + jc * JCL) * HID) + lane;
  float s0 = 0.f, s1 = 0.f, s2 = 0.f, s3 = 0.f;
  float4 v = vp[0];
  #pragma unroll 4
  for (int j = 0; j < JCL; ++j) {
    float4 vn;
    if (j + 1 < JCL) vn = vp[(j + 1) * 64];     // preload next (pipelined)
    s0 = fmaf(fmaxf(a0.x + v.x, 0.f), w.x, s0);
    s1 = fmaf(fmaxf(a1.x + v.x, 0.f), w.x, s1);
    s2 = fmaf(fmaxf(a2.x + v.x, 0.f), w.x, s2);
    s3 = fmaf(fmaxf(a3.x + v.x, 0.f), w.x, s3);
    s0 = fmaf(fmaxf(a0.y + v.y, 0.f), w.y, s0);
    s1 = fmaf(fmaxf(a1.y + v.y, 0.f), w.y, s1);
    s2 = fmaf(fmaxf(a2.y + v.y, 0.f), w.y, s2);
    s3 = fmaf(fmaxf(a3.y + v.y, 0.f), w.y, s3);
    s0 = fmaf(fmaxf(a0.z + v.z, 0.f), w.z, s0);
    s1 = fmaf(fmaxf(a1.z + v.z, 0.f), w.z, s1);
    s2 = fmaf(fmaxf(a2.z + v.z, 0.f), w.z, s2);
    s3 = fmaf(fmaxf(a3.z + v.z, 0.f), w.z, s3);
    s0 = fmaf(fmaxf(a0.w + v.w, 0.f), w.w, s0);
    s1 = fmaf(fmaxf(a1.w + v.w, 0.f), w.w, s1);
    s2 = fmaf(fmaxf(a2.w + v.w, 0.f), w.w, s2);
    s3 = fmaf(fmaxf(a3.w + v.w, 0.f), w.w, s3);
    v = vn;
  }

  #pragma unroll
  for (int off = 32; off > 0; off >>= 1) {
    s0 += __shfl_down(s0, off);
    s1 += __shfl_down(s1, off);
    s2 += __shfl_down(s2, off);
    s3 += __shfl_down(s3, off);
  }
  if (lane == 0) {
    float* pp = partial + (b * NJC + jc) * L_DIM;
    pp[wi          ] = s0;
    pp[wi + 1 * NIW] = s1;
    pp[wi + 2 * NIW] = s2;
    pp[wi + 3 * NIW] = s3;
  }

  // ---- fused final reduce: last block to arrive does it (release/acquire) ----
  __threadfence();                              // release partial writes
  __shared__ int ticket;
  if (threadIdx.x == 0) ticket = atomicAdd(counter, 1);
  __syncthreads();
  if (ticket == PAIR_BLOCKS - 1) {
    __threadfence();                            // acquire others' writes
    const volatile float* vpart = partial;
    __shared__ float sred[B_DIM][4];
    for (int bb = 0; bb < B_DIM; ++bb) {
      float acc = 0.0f;
      for (int idx = threadIdx.x; idx < NJC * L_DIM; idx += 256)
        acc += vpart[bb * NJC * L_DIM + idx];   // fixed order -> deterministic
      #pragma unroll
      for (int off = 32; off > 0; off >>= 1) acc += __shfl_down(acc, off);
      if (lane == 0) sred[bb][threadIdx.x >> 6] = acc;
    }
    __syncthreads();
    if (threadIdx.x < B_DIM)
      out[threadIdx.x] = sred[threadIdx.x][0] + sred[threadIdx.x][1]
                       + sred[threadIdx.x][2] + sred[threadIdx.x][3]
                       + (float)(L_DIM * L_DIM) * b2[0];
  }
}

extern "C" void kernel_launch(void* const* d_in, const int* in_sizes, int n_in,
                              void* d_out, int out_size, void* d_ws, size_t ws_size,
                              hipStream_t stream) {
  const float* f1 = (const float*)d_in[0];   // [B, C, 14, 14]
  const float* f2 = (const float*)d_in[1];
  const float* W1 = (const float*)d_in[2];   // [2C, HID]
  const float* b1 = (const float*)d_in[3];   // [HID]
  const float* W2 = (const float*)d_in[4];   // [HID, 1]
  const float* b2 = (const float*)d_in[5];   // [1]
  float* out = (float*)d_out;                // [B, 1]

  float* p1      = (float*)d_ws;
  float* p2      = p1 + P_ELEMS;
  float* partial = p2 + P_ELEMS;
  int*   counter = (int*)(partial + PARTIAL_ELEMS);

  dim3 g1(224, 2);                           // (112 b*l-tiles x 2 h-halves, 2 sides)
  compute_p_kernel<<<g1, 512, 0, stream>>>(f1, f2, W1, b1, p1, p2, counter);

  pair_kernel<<<PAIR_BLOCKS, 256, 0, stream>>>(p1, p2, W2, b2, partial, counter, out);
}

// Round 4
// 44.286 us; speedup vs baseline: 2.3725x; 2.3725x over previous
//
#include <hip/hip_runtime.h>

#define C_DIM 512
#define HID   256
#define B_DIM 8
#define L_DIM 196
#define LT    14                // l-tile per block (phase 1)
#define NCH   4                 // c-chunks = waves per block (phase 1)
#define CCH   (C_DIM/NCH)       // 128 c per chunk
#define HS    64                // h-strip per block (phase 1) = lane width
#define ROWS  14                // i-rows per wave (phase 2)
#define NJC   14                // j-chunks (phase 2)
#define JCL   (L_DIM/NJC)       // 14 j per chunk
#define PAIR_WAVES (B_DIM*NJC*LT)           // 1568
#define PAIR_BLOCKS (PAIR_WAVES/4)          // 392
#define P_ELEMS        (B_DIM*L_DIM*HID)
#define PARTIAL_ELEMS  (B_DIM*NJC*L_DIM)    // 21952

// Phase 1: p1[b,l,h] = sum_c f1[b,c,l]*W1[c,h] + b1[h]
//          p2[b,l,h] = sum_c f2[b,c,l]*W1[C+c,h]
// grid = (8*14*4, 2), block = 256 = 4 waves; wave = c-chunk, lane = h within strip.
__global__ __launch_bounds__(256) void compute_p_kernel(
    const float* __restrict__ f1, const float* __restrict__ f2,
    const float* __restrict__ W1, const float* __restrict__ b1,
    float* __restrict__ p1, float* __restrict__ p2) {
  const int which = blockIdx.y;
  const int hs = blockIdx.x & 3;
  const int bt = blockIdx.x >> 2;               // 0..111
  const int b  = bt / 14;
  const int l0 = (bt % 14) * LT;
  const int lane  = threadIdx.x & 63;
  const int chunk = threadIdx.x >> 6;           // 0..3 (wave id)
  const int h = hs * HS + lane;

  const float* __restrict__ f = which ? f2 : f1;
  const float* __restrict__ W = W1 + which * C_DIM * HID;
  float* __restrict__ p = which ? p2 : p1;

  __shared__ float fv[C_DIM][16];               // 32 KB, rows padded to 64 B
  float (*comb)[HS][LT + 1] = (float (*)[HS][LT + 1])fv;   // aliased after c-loop

  for (int idx = threadIdx.x; idx < C_DIM * LT; idx += 256) {
    const int c  = idx / LT;
    const int lt = idx - c * LT;
    fv[c][lt] = f[(b * C_DIM + c) * L_DIM + l0 + lt];
  }

  float acc[LT];
  #pragma unroll
  for (int lt = 0; lt < LT; ++lt) acc[lt] = 0.0f;
  __syncthreads();

  const float* __restrict__ Wc = W + (chunk * CCH) * HID + h;   // wave: 256B coalesced
  const float4* __restrict__ fr = (const float4*)fv[chunk * CCH];
  #pragma unroll 8
  for (int c = 0; c < CCH; ++c) {
    const float w = Wc[c * HID];
    const float4 v0 = fr[c * 4 + 0];            // LDS broadcast reads (free)
    const float4 v1 = fr[c * 4 + 1];
    const float4 v2 = fr[c * 4 + 2];
    const float4 v3 = fr[c * 4 + 3];
    acc[ 0] = fmaf(v0.x, w, acc[ 0]);
    acc[ 1] = fmaf(v0.y, w, acc[ 1]);
    acc[ 2] = fmaf(v0.z, w, acc[ 2]);
    acc[ 3] = fmaf(v0.w, w, acc[ 3]);
    acc[ 4] = fmaf(v1.x, w, acc[ 4]);
    acc[ 5] = fmaf(v1.y, w, acc[ 5]);
    acc[ 6] = fmaf(v1.z, w, acc[ 6]);
    acc[ 7] = fmaf(v1.w, w, acc[ 7]);
    acc[ 8] = fmaf(v2.x, w, acc[ 8]);
    acc[ 9] = fmaf(v2.y, w, acc[ 9]);
    acc[10] = fmaf(v2.z, w, acc[10]);
    acc[11] = fmaf(v2.w, w, acc[11]);
    acc[12] = fmaf(v3.x, w, acc[12]);
    acc[13] = fmaf(v3.y, w, acc[13]);
  }

  __syncthreads();                              // fv dead beyond rows 0..137 readers done
  if (chunk >= 2) {
    #pragma unroll
    for (int lt = 0; lt < LT; ++lt) comb[chunk - 2][lane][lt] = acc[lt];
  }
  __syncthreads();
  if (chunk < 2) {
    #pragma unroll
    for (int lt = 0; lt < LT; ++lt) acc[lt] += comb[chunk][lane][lt];
  }
  __syncthreads();
  if (chunk == 1) {
    #pragma unroll
    for (int lt = 0; lt < LT; ++lt) comb[0][lane][lt] = acc[lt];
  }
  __syncthreads();
  if (chunk == 0) {
    const float bias = which ? 0.0f : b1[h];    // fold b1 into p1 only
    #pragma unroll
    for (int lt = 0; lt < LT; ++lt)
      p[(b * L_DIM + l0 + lt) * HID + h] = acc[lt] + comb[0][lane][lt] + bias;
  }
}

// Phase 2: wave = 14 i-rows x one 14-j chunk.
// partial[b,jc,i] = sum_{j in chunk jc} relu(p1[b,i,:]+p2[b,j,:]).W2
// No fences, no atomics. 1568 waves.
__global__ __launch_bounds__(256) void pair_kernel(
    const float* __restrict__ p1, const float* __restrict__ p2,
    const float* __restrict__ W2, float* __restrict__ partial) {
  const int lane = threadIdx.x & 63;
  const int wid  = blockIdx.x * 4 + (threadIdx.x >> 6);   // 0..1567
  const int b  = wid / (NJC * LT);                        // /196
  const int r  = wid % (NJC * LT);
  const int jc = r / LT;                                  // 0..13
  const int wi = r % LT;                                  // 0..13

  const float4 w = *(const float4*)(W2 + lane * 4);
  const float* __restrict__ p1b = p1 + (b * L_DIM) * HID + lane * 4;

  float4 a[ROWS];
  #pragma unroll
  for (int k = 0; k < ROWS; ++k)
    a[k] = *(const float4*)(p1b + (wi + k * LT) * HID);   // i = wi + k*14

  float s[ROWS];
  #pragma unroll
  for (int k = 0; k < ROWS; ++k) s[k] = 0.0f;

  const float4* __restrict__ vp =
      (const float4*)(p2 + (b * L_DIM + jc * JCL) * HID) + lane;

#define PAIR_BODY(vv)                                          \
  {                                                            \
    _Pragma("unroll")                                          \
    for (int k = 0; k < ROWS; ++k) {                           \
      s[k] = fmaf(fmaxf(a[k].x + (vv).x, 0.f), w.x, s[k]);     \
      s[k] = fmaf(fmaxf(a[k].y + (vv).y, 0.f), w.y, s[k]);     \
      s[k] = fmaf(fmaxf(a[k].z + (vv).z, 0.f), w.z, s[k]);     \
      s[k] = fmaf(fmaxf(a[k].w + (vv).w, 0.f), w.w, s[k]);     \
    }                                                          \
  }

  float4 v = vp[0];
  #pragma unroll
  for (int j = 0; j < JCL - 1; ++j) {           // no conditional in the pipeline
    float4 vn = vp[(j + 1) * 64];
    PAIR_BODY(v);
    v = vn;
  }
  PAIR_BODY(v);
#undef PAIR_BODY

  #pragma unroll
  for (int off = 32; off > 0; off >>= 1) {
    #pragma unroll
    for (int k = 0; k < ROWS; ++k) s[k] += __shfl_down(s[k], off);
  }
  if (lane == 0) {
    float* pp = partial + (b * NJC + jc) * L_DIM;
    #pragma unroll
    for (int k = 0; k < ROWS; ++k) pp[wi + k * LT] = s[k];
  }
}

// Phase 3: out[b] = sum over NJC*L partials + L*L*b2
__global__ __launch_bounds__(256) void reduce_kernel(
    const float* __restrict__ partial, const float* __restrict__ b2,
    float* __restrict__ out) {
  const int b = blockIdx.x;
  const int t = threadIdx.x;
  float acc = 0.0f;
  for (int idx = t; idx < NJC * L_DIM; idx += 256)
    acc += partial[b * NJC * L_DIM + idx];
  #pragma unroll
  for (int off = 32; off > 0; off >>= 1) acc += __shfl_down(acc, off);
  __shared__ float sred[4];
  if ((t & 63) == 0) sred[t >> 6] = acc;
  __syncthreads();
  if (t == 0)
    out[b] = sred[0] + sred[1] + sred[2] + sred[3]
           + (float)(L_DIM * L_DIM) * b2[0];
}

extern "C" void kernel_launch(void* const* d_in, const int* in_sizes, int n_in,
                              void* d_out, int out_size, void* d_ws, size_t ws_size,
                              hipStream_t stream) {
  const float* f1 = (const float*)d_in[0];   // [B, C, 14, 14]
  const float* f2 = (const float*)d_in[1];
  const float* W1 = (const float*)d_in[2];   // [2C, HID]
  const float* b1 = (const float*)d_in[3];   // [HID]
  const float* W2 = (const float*)d_in[4];   // [HID, 1]
  const float* b2 = (const float*)d_in[5];   // [1]
  float* out = (float*)d_out;                // [B, 1]

  float* p1      = (float*)d_ws;
  float* p2      = p1 + P_ELEMS;
  float* partial = p2 + P_ELEMS;

  dim3 g1(B_DIM * 14 * 4, 2);                // (b, l-tile, h-strip) x side
  compute_p_kernel<<<g1, 256, 0, stream>>>(f1, f2, W1, b1, p1, p2);

  pair_kernel<<<PAIR_BLOCKS, 256, 0, stream>>>(p1, p2, W2, partial);

  reduce_kernel<<<B_DIM, 256, 0, stream>>>(partial, b2, out);
}